// Round 1
// baseline (1514.150 us; speedup 1.0000x reference)
//
#include <hip/hip_runtime.h>
#include <stdint.h>

typedef unsigned short u16;
typedef __bf16 bf16x8_t __attribute__((ext_vector_type(8)));
typedef float f32x4_t __attribute__((ext_vector_type(4)));
typedef u16 u16x8 __attribute__((ext_vector_type(8)));

#define DEVINL static __device__ __forceinline__

DEVINL float b2f(u16 h){ union{unsigned u; float f;} v; v.u=((unsigned)h)<<16; return v.f; }
DEVINL u16 f2b(float f){ union{float f; unsigned u;} v; v.f=f; unsigned u=v.u; u += 0x7fffu + ((u>>16)&1u); return (u16)(u>>16); }

DEVINL void gload16(const void* g, void* lds){
  __builtin_amdgcn_global_load_lds((__attribute__((address_space(1))) void*)(void*)g,
                                   (__attribute__((address_space(3))) void*)lds, 16, 0, 0);
}

// block-wide (256 thr) sum of two floats; sm = shared float[8]
DEVINL void blk_sum2(float& a, float& b, float* sm){
  #pragma unroll
  for (int o=32;o;o>>=1){ a += __shfl_down(a,o,64); b += __shfl_down(b,o,64); }
  int tid = threadIdx.x;
  if ((tid&63)==0){ sm[(tid>>6)*2]=a; sm[(tid>>6)*2+1]=b; }
  __syncthreads();
  a = sm[0]+sm[2]+sm[4]+sm[6];
  b = sm[1]+sm[3]+sm[5]+sm[7];
  __syncthreads();
}

// ---------------- GEMM: C[M,N] = A[M,K] @ B^T, B stored [N][K] (both bf16/u16) ----------------
// BM=BN=128, BK=32, 256 threads = 4 waves in 2x2, each wave 64x64 (4x4 16x16x32 MFMA frags).
template<int EPI>  // 0: bf16 store, 1: bf16 relu store, 2: f32 store
__global__ __launch_bounds__(256) void gemm_k(
    const u16* __restrict__ A, int lda, long aS1, long aS2,
    const u16* __restrict__ B, int ldb, long bS1, long bS2,
    void* __restrict__ Cv, int ldc, long cS1, long cS2,
    int K, int zdiv)
{
  __shared__ u16 sA[128*32];
  __shared__ u16 sB[128*32];
  const int tid = threadIdx.x;
  const int w = tid >> 6, l = tid & 63;
  const int z = blockIdx.z; const int z1 = z / zdiv, z2 = z % zdiv;
  const u16* Ab = A + z1*aS1 + z2*aS2;
  const u16* Bb = B + z1*bS1 + z2*bS2;
  const int rowB = blockIdx.y * 128, colB = blockIdx.x * 128;

  const int sr = w*32 + (l>>2);      // staging row within tile
  const int so = (l&3)*8;            // staging k-offset (elements)
  const u16* gA0 = Ab + (long)(rowB + sr)*lda + so;
  const u16* gA1 = gA0 + (long)16*lda;
  const u16* gB0 = Bb + (long)(colB + sr)*ldb + so;
  const u16* gB1 = gB0 + (long)16*ldb;
  u16* lA0 = sA + w*1024; u16* lA1 = lA0 + 512;   // wave-uniform LDS dests
  u16* lB0 = sB + w*1024; u16* lB1 = lB0 + 512;

  const int lrow = l & 15, lg = l >> 4;
  const int wrow = w & 1, wcol = w >> 1;

  f32x4_t zz = {0.f,0.f,0.f,0.f};
  f32x4_t acc[4][4];
  #pragma unroll
  for (int mi=0; mi<4; ++mi)
    #pragma unroll
    for (int ni=0; ni<4; ++ni) acc[mi][ni] = zz;

  for (int k0 = 0; k0 < K; k0 += 32) {
    __syncthreads();
    gload16(gA0 + k0, lA0);
    gload16(gA1 + k0, lA1);
    gload16(gB0 + k0, lB0);
    gload16(gB1 + k0, lB1);
    __syncthreads();
    bf16x8_t af[4], bfr[4];
    #pragma unroll
    for (int mi=0; mi<4; ++mi)
      af[mi] = *(const bf16x8_t*)&sA[(wrow*64 + mi*16 + lrow)*32 + lg*8];
    #pragma unroll
    for (int ni=0; ni<4; ++ni)
      bfr[ni] = *(const bf16x8_t*)&sB[(wcol*64 + ni*16 + lrow)*32 + lg*8];
    #pragma unroll
    for (int mi=0; mi<4; ++mi)
      #pragma unroll
      for (int ni=0; ni<4; ++ni)
        acc[mi][ni] = __builtin_amdgcn_mfma_f32_16x16x32_bf16(af[mi], bfr[ni], acc[mi][ni], 0,0,0);
  }

  const long cb = z1*cS1 + z2*cS2;
  #pragma unroll
  for (int mi=0; mi<4; ++mi)
  #pragma unroll
  for (int ni=0; ni<4; ++ni)
  #pragma unroll
  for (int j=0; j<4; ++j) {
    const long rr = rowB + wrow*64 + mi*16 + lg*4 + j;
    const long cc = colB + wcol*64 + ni*16 + lrow;
    float v = acc[mi][ni][j];
    if (EPI == 2) ((float*)Cv)[cb + rr*(long)ldc + cc] = v;
    else {
      if (EPI == 1) v = fmaxf(v, 0.f);
      ((u16*)Cv)[cb + rr*(long)ldc + cc] = f2b(v);
    }
  }
}

// ---------------- weight prep ----------------
// transpose+convert: src f32 [R][Cc] -> dst bf16 [Cc][R]
__global__ __launch_bounds__(256) void k_tcvt(const float* __restrict__ src, u16* __restrict__ dst, int R, int Cc){
  __shared__ float s[32][33];
  int c0 = blockIdx.x*32, r0 = blockIdx.y*32;
  int tx = threadIdx.x, ty = threadIdx.y;
  #pragma unroll
  for (int k=0;k<4;++k)
    s[ty+8*k][tx] = src[(long)(r0+ty+8*k)*Cc + c0+tx];
  __syncthreads();
  #pragma unroll
  for (int k=0;k<4;++k)
    dst[(long)(c0+ty+8*k)*R + r0+tx] = f2b(s[tx][ty+8*k]);
}

// elementwise convert f32->bf16 (grid*1024 elements)
__global__ __launch_bounds__(256) void k_cvt(const float* __restrict__ src, u16* __restrict__ dst){
  long base = (long)blockIdx.x*1024 + threadIdx.x;
  #pragma unroll
  for (int j=0;j<4;++j) dst[base + j*256] = f2b(src[base + j*256]);
}

// c1R [O=1024][I=1024][T=3] -> dst[o][t*1024+i] bf16   grid(1024,12)
__global__ __launch_bounds__(256) void k_c1rp(const float* __restrict__ src, u16* __restrict__ dst){
  int o = blockIdx.x; int kk = blockIdx.y*256 + threadIdx.x;
  int i = kk & 1023, t = kk >> 10;
  dst[(long)o*3072 + kk] = f2b(src[(long)o*3072 + i*3 + t]);
}

__global__ void k_zero(float* p){ if (threadIdx.x < 2) p[threadIdx.x] = 0.f; }

// ---------------- bottleneck ----------------
// y[b,h,w] = sum_c x[b,c,h,w]*blw[c]; write X[b][w][h] (pre-BN); accumulate sum/sumsq
__global__ __launch_bounds__(256) void k_bneck1(const float* __restrict__ x, const float* __restrict__ blw,
                                                float* __restrict__ X, float* __restrict__ stats){
  __shared__ float s[64][65];
  __shared__ float red[8];
  int b = blockIdx.z, h0 = blockIdx.y*64, w0 = blockIdx.x*64;
  int tid = threadIdx.x;
  int wl = tid & 63, hl = tid >> 6;
  float yacc[16];
  #pragma unroll
  for (int r=0;r<16;++r) yacc[r]=0.f;
  for (int c=0;c<16;++c){
    float wc = blw[c];
    const float* xp = x + (((long)(b*16 + c)*1024 + h0)*512 + w0);
    #pragma unroll
    for (int r=0;r<16;++r)
      yacc[r] += xp[(hl + 4*r)*512 + wl] * wc;
  }
  float s1=0.f, s2=0.f;
  #pragma unroll
  for (int r=0;r<16;++r){ s1+=yacc[r]; s2+=yacc[r]*yacc[r]; }
  #pragma unroll
  for (int o=32;o;o>>=1){ s1+=__shfl_down(s1,o,64); s2+=__shfl_down(s2,o,64); }
  if ((tid&63)==0){ red[(tid>>6)*2]=s1; red[(tid>>6)*2+1]=s2; }
  #pragma unroll
  for (int r=0;r<16;++r) s[hl+4*r][wl] = yacc[r];
  __syncthreads();
  if (tid==0){
    atomicAdd(&stats[0], red[0]+red[2]+red[4]+red[6]);
    atomicAdd(&stats[1], red[1]+red[3]+red[5]+red[7]);
  }
  #pragma unroll
  for (int r=0;r<16;++r)
    X[((long)(b*512) + w0 + hl + 4*r)*1024 + h0 + wl] = s[wl][hl+4*r];
}

// BN(affine scalar)+ReLU in place; also write bf16 copy
__global__ __launch_bounds__(256) void k_bneck2(float* __restrict__ X, u16* __restrict__ Xb,
                                                const float* __restrict__ stats,
                                                const float* __restrict__ bnw, const float* __restrict__ bnb){
  long base = (long)blockIdx.x*1024 + threadIdx.x;
  float mean = stats[0] * (1.f/4194304.f);
  float var  = stats[1] * (1.f/4194304.f) - mean*mean;
  float inv  = 1.f/sqrtf(var + 1e-5f);
  float w = bnw[0], bb = bnb[0];
  #pragma unroll
  for (int j=0;j<4;++j){
    float v = X[base + j*256];
    v = fmaxf((v - mean)*inv*w + bb, 0.f);
    X[base + j*256] = v; Xb[base + j*256] = f2b(v);
  }
}

// ---------------- row LN kernels ----------------
// GLU: u = X + a*sigmoid(b), LN -> X (f32) & Xb (bf16). g is [4096][2048] bf16.
__global__ __launch_bounds__(256) void k_glu_ln(const u16* __restrict__ g, float* __restrict__ X, u16* __restrict__ Xb,
                                                const float* __restrict__ lw, const float* __restrict__ lb){
  __shared__ float sm[8];
  long r = blockIdx.x; int tid = threadIdx.x;
  float u[4]; float s1=0.f, s2=0.f;
  #pragma unroll
  for (int j=0;j<4;++j){
    int i = j*256 + tid;
    float xv = X[r*1024 + i];
    float av = b2f(g[r*2048 + i]);
    float bv = b2f(g[r*2048 + 1024 + i]);
    float t = xv + av * (1.f/(1.f + expf(-bv)));
    u[j]=t; s1+=t; s2+=t*t;
  }
  blk_sum2(s1,s2,sm);
  float m = s1*(1.f/1024.f), var = s2*(1.f/1024.f)-m*m;
  float inv = 1.f/sqrtf(var+1e-5f);
  #pragma unroll
  for (int j=0;j<4;++j){
    int i=j*256+tid;
    float o = (u[j]-m)*inv*lw[i]+lb[i];
    X[r*1024+i]=o; Xb[r*1024+i]=f2b(o);
  }
}

// residual + LN over 1024: u = X + T(bf16); -> X, Xb
__global__ __launch_bounds__(256) void k_res_ln(float* __restrict__ X, const u16* __restrict__ T, u16* __restrict__ Xb,
                                                const float* __restrict__ lw, const float* __restrict__ lb){
  __shared__ float sm[8];
  long r = blockIdx.x; int tid = threadIdx.x;
  float u[4]; float s1=0.f, s2=0.f;
  #pragma unroll
  for (int j=0;j<4;++j){
    int i = j*256 + tid;
    float t = X[r*1024 + i] + b2f(T[r*1024 + i]);
    u[j]=t; s1+=t; s2+=t*t;
  }
  blk_sum2(s1,s2,sm);
  float m = s1*(1.f/1024.f), var = s2*(1.f/1024.f)-m*m;
  float inv = 1.f/sqrtf(var+1e-5f);
  #pragma unroll
  for (int j=0;j<4;++j){
    int i=j*256+tid;
    float o = (u[j]-m)*inv*lw[i]+lb[i];
    X[r*1024+i]=o; Xb[r*1024+i]=f2b(o);
  }
}

// h = LN(hL + pad(hR)) over 4096, output bf16
__global__ __launch_bounds__(256) void k_add_ln4096(const u16* __restrict__ hL, const u16* __restrict__ hR,
                                                    u16* __restrict__ H,
                                                    const float* __restrict__ lw, const float* __restrict__ lb){
  __shared__ float sm[8];
  long r = blockIdx.x; int tid = threadIdx.x;
  float u[16]; float s1=0.f, s2=0.f;
  #pragma unroll
  for (int j=0;j<16;++j){
    int i = j*256 + tid;
    float t = b2f(hL[r*4096 + i]);
    if (j < 4) t += b2f(hR[r*1024 + i]);
    u[j]=t; s1+=t; s2+=t*t;
  }
  blk_sum2(s1,s2,sm);
  float m = s1*(1.f/4096.f), var = s2*(1.f/4096.f)-m*m;
  float inv = 1.f/sqrtf(var+1e-5f);
  #pragma unroll
  for (int j=0;j<16;++j){
    int i=j*256+tid;
    H[r*4096+i] = f2b((u[j]-m)*inv*lw[i]+lb[i]);
  }
}

// ---------------- conv path ----------------
// Abig[(b,w)][t*1024+i] = Xb[b, w+t-1, i] (zero pad)
__global__ __launch_bounds__(256) void k_gather(const u16* __restrict__ Xb, u16* __restrict__ Ab){
  int r = blockIdx.x;
  int b = r >> 9, wp = r & 511;
  for (int c = threadIdx.x; c < 384; c += 256){
    int t = c >> 7;
    int i0 = (c & 127) * 8;
    int ws_ = wp + t - 1;
    u16x8 v = {0,0,0,0,0,0,0,0};
    if (ws_ >= 0 && ws_ < 512) v = *(const u16x8*)&Xb[((long)(b*512+ws_))*1024 + i0];
    *(u16x8*)&Ab[(long)r*3072 + t*1024 + i0] = v;
  }
}

// depthwise conv k=9 over w: HC[(b,w)][f] = sum_t H[(b,w+t-4)][f]*cd[f*9+t]
__global__ __launch_bounds__(256) void k_dw(const u16* __restrict__ H, const float* __restrict__ cd,
                                            u16* __restrict__ HC){
  int r = blockIdx.y;
  int f0 = (blockIdx.x*256 + threadIdx.x)*8;
  int b = r>>9, wp = r&511;
  float acc[8] = {0.f,0.f,0.f,0.f,0.f,0.f,0.f,0.f};
  #pragma unroll
  for (int t=0;t<9;++t){
    int ww = wp + t - 4;
    if (ww < 0 || ww >= 512) continue;
    u16x8 hv = *(const u16x8*)&H[((long)(b*512+ww))*4096 + f0];
    #pragma unroll
    for (int e=0;e<8;++e) acc[e] += b2f(hv[e]) * cd[(f0+e)*9 + t];
  }
  u16x8 o;
  #pragma unroll
  for (int e=0;e<8;++e) o[e] = f2b(acc[e]);
  *(u16x8*)&HC[(long)r*4096 + f0] = o;
}

// transpose v [per (b,n): 512 x 256, lda 1024] -> vT [32][256][512]
__global__ __launch_bounds__(256) void k_tv(const u16* __restrict__ V, u16* __restrict__ VT){
  __shared__ u16 s[32][33];
  int z = blockIdx.z; int b = z>>2, n = z&3;
  int d0 = blockIdx.x*32, i0 = blockIdx.y*32;
  int tx = threadIdx.x, ty = threadIdx.y;
  const u16* src = V + (long)(b*512)*1024 + n*256;
  #pragma unroll
  for (int k=0;k<4;++k)
    s[ty+8*k][tx] = src[(long)(i0+ty+8*k)*1024 + d0 + tx];
  __syncthreads();
  u16* dst = VT + (long)z*131072;
  #pragma unroll
  for (int k=0;k<4;++k)
    dst[(long)(d0+ty+8*k)*512 + i0 + tx] = s[tx][ty+8*k];
}

// ---------------- attention softmax ----------------
// scores = S/32 + |i-j|/2 * dw[n,i] + Et ; softmax over j ; P bf16
__global__ __launch_bounds__(256) void k_softmax(const float* __restrict__ S, const u16* __restrict__ Et,
                                                 const float* __restrict__ dw, u16* __restrict__ P){
  __shared__ float sm[8];
  int id = blockIdx.x;
  int i = id & 511, n = (id>>9)&3;
  long base = (long)id * 512;
  float dwv = dw[n*512 + i];
  int tid = threadIdx.x;
  float sv[2]; float mx = -1e30f;
  #pragma unroll
  for (int j2=0;j2<2;++j2){
    int j = j2*256 + tid;
    float t = S[base+j]*0.03125f + fabsf((float)(i-j))*0.5f*dwv + b2f(Et[base+j]);
    sv[j2]=t; mx = fmaxf(mx,t);
  }
  #pragma unroll
  for (int o=32;o;o>>=1) mx = fmaxf(mx, __shfl_down(mx,o,64));
  if ((tid&63)==0) sm[tid>>6]=mx;
  __syncthreads();
  mx = fmaxf(fmaxf(sm[0],sm[1]),fmaxf(sm[2],sm[3]));
  __syncthreads();
  float ev[2]; float s1=0.f;
  #pragma unroll
  for (int j2=0;j2<2;++j2){ ev[j2]=expf(sv[j2]-mx); s1+=ev[j2]; }
  #pragma unroll
  for (int o=32;o;o>>=1) s1 += __shfl_down(s1,o,64);
  if ((tid&63)==0) sm[tid>>6]=s1;
  __syncthreads();
  s1 = sm[0]+sm[1]+sm[2]+sm[3];
  float rr = 1.f/s1;
  #pragma unroll
  for (int j2=0;j2<2;++j2) P[base + j2*256 + tid] = f2b(ev[j2]*rr);
}

// ---------------- final transpose: out[b][h][w] = X[b][w][h] ----------------
__global__ __launch_bounds__(256) void k_final(const float* __restrict__ X, float* __restrict__ out){
  __shared__ float s[64][65];
  int b = blockIdx.z, h0 = blockIdx.y*64, w0 = blockIdx.x*64;
  int tid = threadIdx.x;
  int a = tid & 63, q = tid >> 6;
  #pragma unroll
  for (int r=0;r<16;++r)
    s[q+4*r][a] = X[((long)(b*512)+w0+q+4*r)*1024 + h0 + a];
  __syncthreads();
  #pragma unroll
  for (int r=0;r<16;++r)
    out[((long)(b*1024)+h0+q+4*r)*512 + w0 + a] = s[a][q+4*r];
}

// ---------------- host ----------------
extern "C" void kernel_launch(void* const* d_in, const int* in_sizes, int n_in,
                              void* d_out, int out_size, void* d_ws, size_t ws_size,
                              hipStream_t stream) {
  const float* x      = (const float*)d_in[0];
  const float* bl_w   = (const float*)d_in[1];
  const float* bn_w   = (const float*)d_in[2];
  const float* bn_b   = (const float*)d_in[3];
  const float* glu_w  = (const float*)d_in[4];
  const float* ln1_w  = (const float*)d_in[5];
  const float* ln1_b  = (const float*)d_in[6];
  const float* c1L_w  = (const float*)d_in[7];
  const float* c1R_w  = (const float*)d_in[8];
  const float* ln2_w  = (const float*)d_in[9];
  const float* ln2_b  = (const float*)d_in[10];
  const float* c2d_w  = (const float*)d_in[11];
  const float* c2p_w  = (const float*)d_in[12];
  const float* ln3_w  = (const float*)d_in[13];
  const float* ln3_b  = (const float*)d_in[14];
  const float* q_w    = (const float*)d_in[15];
  const float* k_w    = (const float*)d_in[16];
  const float* v_w    = (const float*)d_in[17];
  const float* o_w    = (const float*)d_in[18];
  const float* er     = (const float*)d_in[19];
  const float* dist_w = (const float*)d_in[20];
  const float* ln4_w  = (const float*)d_in[21];
  const float* ln4_b  = (const float*)d_in[22];
  const float* c3_w   = (const float*)d_in[23];
  const float* c4_w   = (const float*)d_in[24];
  const float* ln5_w  = (const float*)d_in[25];
  const float* ln5_b  = (const float*)d_in[26];

  char* ws = (char*)d_ws;
  size_t off = 0;
  auto alloc = [&](size_t n){ size_t o = off; off = (off + n + 255) & ~(size_t)255; return o; };

  size_t o_wglu = alloc(2048ull*1024*2);
  size_t o_wc1L = alloc(4096ull*1024*2);
  size_t o_wc1R = alloc(1024ull*3072*2);
  size_t o_wc2p = alloc(1024ull*4096*2);
  size_t o_wq   = alloc(1024ull*1024*2);
  size_t o_wk   = alloc(1024ull*1024*2);
  size_t o_wv   = alloc(1024ull*1024*2);
  size_t o_wo   = alloc(1024ull*1024*2);
  size_t o_wert = alloc(512ull*256*2);
  size_t o_wc3  = alloc(4096ull*1024*2);
  size_t o_wc4  = alloc(1024ull*4096*2);
  size_t o_X    = alloc(4096ull*1024*4);
  size_t o_Xb   = alloc(4096ull*1024*2);
  size_t o_A1   = alloc(33554432);
  size_t o_A2   = alloc(33554432);
  size_t o_A3   = alloc(33554432);
  size_t o_A4   = alloc(16777216);
  size_t o_st   = alloc(256);
  (void)ws_size; (void)n_in; (void)in_sizes; (void)out_size;

  u16* WGLU = (u16*)(ws+o_wglu); u16* WC1L = (u16*)(ws+o_wc1L); u16* WC1R = (u16*)(ws+o_wc1R);
  u16* WC2P = (u16*)(ws+o_wc2p); u16* WQ = (u16*)(ws+o_wq); u16* WK = (u16*)(ws+o_wk);
  u16* WV = (u16*)(ws+o_wv); u16* WO = (u16*)(ws+o_wo); u16* WERT = (u16*)(ws+o_wert);
  u16* WC3 = (u16*)(ws+o_wc3); u16* WC4 = (u16*)(ws+o_wc4);
  float* X = (float*)(ws+o_X); u16* Xb = (u16*)(ws+o_Xb);
  u16* A1 = (u16*)(ws+o_A1); u16* A2 = (u16*)(ws+o_A2);
  u16* A3 = (u16*)(ws+o_A3); u16* A4 = (u16*)(ws+o_A4);
  float* stats = (float*)(ws+o_st);

  auto GEMM = [&](int epi, const u16* A, int lda, long aS1, long aS2,
                  const u16* B, int ldb, long bS1, long bS2,
                  void* C, int ldc, long cS1, long cS2,
                  int M, int N, int K, int zdiv, int nz){
    dim3 grid(N/128, M/128, nz);
    if (epi==0)      gemm_k<0><<<grid,256,0,stream>>>(A,lda,aS1,aS2,B,ldb,bS1,bS2,C,ldc,cS1,cS2,K,zdiv);
    else if (epi==1) gemm_k<1><<<grid,256,0,stream>>>(A,lda,aS1,aS2,B,ldb,bS1,bS2,C,ldc,cS1,cS2,K,zdiv);
    else             gemm_k<2><<<grid,256,0,stream>>>(A,lda,aS1,aS2,B,ldb,bS1,bS2,C,ldc,cS1,cS2,K,zdiv);
  };

  // ---- weight prep ----
  k_zero<<<1,64,0,stream>>>(stats);
  k_tcvt<<<dim3(64,32),dim3(32,8),0,stream>>>(glu_w, WGLU, 1024, 2048);
  k_tcvt<<<dim3(128,32),dim3(32,8),0,stream>>>(c1L_w, WC1L, 1024, 4096);
  k_c1rp<<<dim3(1024,12),256,0,stream>>>(c1R_w, WC1R);
  k_cvt<<<4096,256,0,stream>>>(c2p_w, WC2P);
  k_tcvt<<<dim3(32,32),dim3(32,8),0,stream>>>(q_w, WQ, 1024, 1024);
  k_tcvt<<<dim3(32,32),dim3(32,8),0,stream>>>(k_w, WK, 1024, 1024);
  k_tcvt<<<dim3(32,32),dim3(32,8),0,stream>>>(v_w, WV, 1024, 1024);
  k_tcvt<<<dim3(32,32),dim3(32,8),0,stream>>>(o_w, WO, 1024, 1024);
  k_tcvt<<<dim3(16,8),dim3(32,8),0,stream>>>(er, WERT, 256, 512);
  k_tcvt<<<dim3(128,32),dim3(32,8),0,stream>>>(c3_w, WC3, 1024, 4096);
  k_tcvt<<<dim3(32,128),dim3(32,8),0,stream>>>(c4_w, WC4, 4096, 1024);

  // ---- bottleneck + BN + ReLU ----
  k_bneck1<<<dim3(8,16,8),256,0,stream>>>(x, bl_w, X, stats);
  k_bneck2<<<4096,256,0,stream>>>(X, Xb, stats, bn_w, bn_b);

  // ---- GLU + LN1 ----
  GEMM(0, Xb,1024,0,0, WGLU,1024,0,0, A1,2048,0,0, 4096,2048,1024, 1,1);
  k_glu_ln<<<4096,256,0,stream>>>(A1, X, Xb, ln1_w, ln1_b);

  // ---- dual branch + LN2 ----
  k_gather<<<4096,256,0,stream>>>(Xb, A3);                         // Abig [4096][3072]
  GEMM(1, Xb,1024,0,0, WC1L,1024,0,0, A1,4096,0,0, 4096,4096,1024, 1,1);   // hL
  GEMM(1, A3,3072,0,0, WC1R,3072,0,0, A4,1024,0,0, 4096,1024,3072, 1,1);   // hR
  k_add_ln4096<<<4096,256,0,stream>>>(A1, A4, A2, ln2_w, ln2_b);   // h -> A2

  // ---- depthwise + pointwise + LN3 ----
  k_dw<<<dim3(2,4096),256,0,stream>>>(A2, c2d_w, A1);              // hc -> A1
  GEMM(0, A1,4096,0,0, WC2P,4096,0,0, A4,1024,0,0, 4096,1024,4096, 1,1);   // pw -> A4
  k_res_ln<<<4096,256,0,stream>>>(X, A4, Xb, ln3_w, ln3_b);

  // ---- attention ----
  u16* Aq = A1;               // [4096][1024]
  u16* Ak = A1 + 4194304;
  u16* Av = A1 + 8388608;
  GEMM(0, Xb,1024,0,0, WQ,1024,0,0, Aq,1024,0,0, 4096,1024,1024, 1,1);
  GEMM(0, Xb,1024,0,0, WK,1024,0,0, Ak,1024,0,0, 4096,1024,1024, 1,1);
  GEMM(0, Xb,1024,0,0, WV,1024,0,0, Av,1024,0,0, 4096,1024,1024, 1,1);
  u16* VT = A2;               // [32][256][512]
  k_tv<<<dim3(8,16,32),dim3(32,8),0,stream>>>(Av, VT);
  float* Sf = (float*)A3;     // [8][4][512][512] f32
  GEMM(2, Aq,1024,524288,256, Ak,1024,524288,256, Sf,512,1048576,262144, 512,512,256, 4,32);
  u16* EtB = (u16*)(ws + o_A2 + 8388608);   // [8][4][512][512] bf16
  GEMM(0, WERT,256,0,0, Aq,1024,524288,256, EtB,512,1048576,262144, 512,512,256, 4,32);
  u16* P = A4;                // probs bf16
  k_softmax<<<16384,256,0,stream>>>(Sf, EtB, dist_w, P);
  u16* Ov = A1;               // [4096][1024] (q/k/v dead)
  GEMM(0, P,512,1048576,262144, VT,512,524288,131072, Ov,1024,524288,256, 512,256,512, 4,32);
  u16* AOp = A3;              // o-proj out
  GEMM(0, Ov,1024,0,0, WO,1024,0,0, AOp,1024,0,0, 4096,1024,1024, 1,1);
  k_res_ln<<<4096,256,0,stream>>>(X, AOp, Xb, ln4_w, ln4_b);

  // ---- FFN + LN5 ----
  GEMM(1, Xb,1024,0,0, WC3,1024,0,0, A1,4096,0,0, 4096,4096,1024, 1,1);
  GEMM(0, A1,4096,0,0, WC4,4096,0,0, A4,1024,0,0, 4096,1024,4096, 1,1);
  k_res_ln<<<4096,256,0,stream>>>(X, A4, Xb, ln5_w, ln5_b);

  // ---- output ----
  k_final<<<dim3(8,16,8),256,0,stream>>>(X, (float*)d_out);
}

// Round 3
// 1301.510 us; speedup vs baseline: 1.1634x; 1.1634x over previous
//
#include <hip/hip_runtime.h>
#include <stdint.h>

typedef unsigned short u16;
typedef __bf16 bf16x8_t __attribute__((ext_vector_type(8)));
typedef float f32x4_t __attribute__((ext_vector_type(4)));
typedef u16 u16x8 __attribute__((ext_vector_type(8)));

#define DEVINL static __device__ __forceinline__

DEVINL float b2f(u16 h){ union{unsigned u; float f;} v; v.u=((unsigned)h)<<16; return v.f; }
DEVINL u16 f2b(float f){ union{float f; unsigned u;} v; v.f=f; unsigned u=v.u; u += 0x7fffu + ((u>>16)&1u); return (u16)(u>>16); }

DEVINL void gload16(const void* g, void* lds){
  __builtin_amdgcn_global_load_lds((__attribute__((address_space(1))) void*)(void*)g,
                                   (__attribute__((address_space(3))) void*)lds, 16, 0, 0);
}

// block-wide (256 thr) sum of two floats; sm = shared float[8]
DEVINL void blk_sum2(float& a, float& b, float* sm){
  #pragma unroll
  for (int o=32;o;o>>=1){ a += __shfl_down(a,o,64); b += __shfl_down(b,o,64); }
  int tid = threadIdx.x;
  if ((tid&63)==0){ sm[(tid>>6)*2]=a; sm[(tid>>6)*2+1]=b; }
  __syncthreads();
  a = sm[0]+sm[2]+sm[4]+sm[6];
  b = sm[1]+sm[3]+sm[5]+sm[7];
  __syncthreads();
}

// ---------------- GEMM: C[M,N] = A[M,K] @ B^T, B stored [N][K] (both bf16/u16) ----------------
// BM=BN=128, BK=32, 256 threads = 4 waves in 2x2, each wave 64x64 (4x4 16x16x32 MFMA frags).
template<int EPI>  // 0: bf16 store, 1: bf16 relu store, 2: f32 store
__global__ __launch_bounds__(256) void gemm_k(
    const u16* __restrict__ A, int lda, long aS1, long aS2,
    const u16* __restrict__ B, int ldb, long bS1, long bS2,
    void* __restrict__ Cv, int ldc, long cS1, long cS2,
    int K, int zdiv)
{
  __shared__ u16 sA[128*32];
  __shared__ u16 sB[128*32];
  const int tid = threadIdx.x;
  const int w = tid >> 6, l = tid & 63;
  const int z = blockIdx.z; const int z1 = z / zdiv, z2 = z % zdiv;
  const u16* Ab = A + z1*aS1 + z2*aS2;
  const u16* Bb = B + z1*bS1 + z2*bS2;
  const int rowB = blockIdx.y * 128, colB = blockIdx.x * 128;

  const int sr = w*32 + (l>>2);      // staging row within tile
  const int so = (l&3)*8;            // staging k-offset (elements)
  const u16* gA0 = Ab + (long)(rowB + sr)*lda + so;
  const u16* gA1 = gA0 + (long)16*lda;
  const u16* gB0 = Bb + (long)(colB + sr)*ldb + so;
  const u16* gB1 = gB0 + (long)16*ldb;
  u16* lA0 = sA + w*1024; u16* lA1 = lA0 + 512;   // wave-uniform LDS dests
  u16* lB0 = sB + w*1024; u16* lB1 = lB0 + 512;

  const int lrow = l & 15, lg = l >> 4;
  const int wrow = w & 1, wcol = w >> 1;

  f32x4_t zz = {0.f,0.f,0.f,0.f};
  f32x4_t acc[4][4];
  #pragma unroll
  for (int mi=0; mi<4; ++mi)
    #pragma unroll
    for (int ni=0; ni<4; ++ni) acc[mi][ni] = zz;

  for (int k0 = 0; k0 < K; k0 += 32) {
    __syncthreads();
    gload16(gA0 + k0, lA0);
    gload16(gA1 + k0, lA1);
    gload16(gB0 + k0, lB0);
    gload16(gB1 + k0, lB1);
    __syncthreads();
    bf16x8_t af[4], bfr[4];
    #pragma unroll
    for (int mi=0; mi<4; ++mi)
      af[mi] = *(const bf16x8_t*)&sA[(wrow*64 + mi*16 + lrow)*32 + lg*8];
    #pragma unroll
    for (int ni=0; ni<4; ++ni)
      bfr[ni] = *(const bf16x8_t*)&sB[(wcol*64 + ni*16 + lrow)*32 + lg*8];
    #pragma unroll
    for (int mi=0; mi<4; ++mi)
      #pragma unroll
      for (int ni=0; ni<4; ++ni)
        acc[mi][ni] = __builtin_amdgcn_mfma_f32_16x16x32_bf16(af[mi], bfr[ni], acc[mi][ni], 0,0,0);
  }

  const long cb = z1*cS1 + z2*cS2;
  #pragma unroll
  for (int mi=0; mi<4; ++mi)
  #pragma unroll
  for (int ni=0; ni<4; ++ni)
  #pragma unroll
  for (int j=0; j<4; ++j) {
    const long rr = rowB + wrow*64 + mi*16 + lg*4 + j;
    const long cc = colB + wcol*64 + ni*16 + lrow;
    float v = acc[mi][ni][j];
    if (EPI == 2) ((float*)Cv)[cb + rr*(long)ldc + cc] = v;
    else {
      if (EPI == 1) v = fmaxf(v, 0.f);
      ((u16*)Cv)[cb + rr*(long)ldc + cc] = f2b(v);
    }
  }
}

// ---------------- weight prep ----------------
// transpose+convert: src f32 [R][Cc] -> dst bf16 [Cc][R]
__global__ __launch_bounds__(256) void k_tcvt(const float* __restrict__ src, u16* __restrict__ dst, int R, int Cc){
  __shared__ float s[32][33];
  int c0 = blockIdx.x*32, r0 = blockIdx.y*32;
  int tx = threadIdx.x, ty = threadIdx.y;
  #pragma unroll
  for (int k=0;k<4;++k)
    s[ty+8*k][tx] = src[(long)(r0+ty+8*k)*Cc + c0+tx];
  __syncthreads();
  #pragma unroll
  for (int k=0;k<4;++k)
    dst[(long)(c0+ty+8*k)*R + r0+tx] = f2b(s[tx][ty+8*k]);
}

// elementwise convert f32->bf16 (grid*1024 elements)
__global__ __launch_bounds__(256) void k_cvt(const float* __restrict__ src, u16* __restrict__ dst){
  long base = (long)blockIdx.x*1024 + threadIdx.x;
  #pragma unroll
  for (int j=0;j<4;++j) dst[base + j*256] = f2b(src[base + j*256]);
}

// c1R [O=1024][I=1024][T=3] -> dst[o][t*1024+i] bf16   grid(1024,12)
__global__ __launch_bounds__(256) void k_c1rp(const float* __restrict__ src, u16* __restrict__ dst){
  int o = blockIdx.x; int kk = blockIdx.y*256 + threadIdx.x;
  int i = kk & 1023, t = kk >> 10;
  dst[(long)o*3072 + kk] = f2b(src[(long)o*3072 + i*3 + t]);
}

// depthwise weight transpose: src [4096][9] -> dst [9][4096] f32.  grid(144)
__global__ __launch_bounds__(256) void k_cdt(const float* __restrict__ src, float* __restrict__ dst){
  int idx = blockIdx.x*256 + threadIdx.x;   // 0..36863
  int t = idx >> 12, f = idx & 4095;
  dst[idx] = src[f*9 + t];
}

__global__ void k_zero(float* p){ if (threadIdx.x < 2) p[threadIdx.x] = 0.f; }

// ---------------- bottleneck ----------------
// y[b,h,w] = sum_c x[b,c,h,w]*blw[c]; write X[b][w][h] (pre-BN); accumulate sum/sumsq
__global__ __launch_bounds__(256) void k_bneck1(const float* __restrict__ x, const float* __restrict__ blw,
                                                float* __restrict__ X, float* __restrict__ stats){
  __shared__ float s[64][65];
  __shared__ float red[8];
  int b = blockIdx.z, h0 = blockIdx.y*64, w0 = blockIdx.x*64;
  int tid = threadIdx.x;
  int wl = tid & 63, hl = tid >> 6;
  float yacc[16];
  #pragma unroll
  for (int r=0;r<16;++r) yacc[r]=0.f;
  for (int c=0;c<16;++c){
    float wc = blw[c];
    const float* xp = x + (((long)(b*16 + c)*1024 + h0)*512 + w0);
    #pragma unroll
    for (int r=0;r<16;++r)
      yacc[r] += xp[(hl + 4*r)*512 + wl] * wc;
  }
  float s1=0.f, s2=0.f;
  #pragma unroll
  for (int r=0;r<16;++r){ s1+=yacc[r]; s2+=yacc[r]*yacc[r]; }
  #pragma unroll
  for (int o=32;o;o>>=1){ s1+=__shfl_down(s1,o,64); s2+=__shfl_down(s2,o,64); }
  if ((tid&63)==0){ red[(tid>>6)*2]=s1; red[(tid>>6)*2+1]=s2; }
  #pragma unroll
  for (int r=0;r<16;++r) s[hl+4*r][wl] = yacc[r];
  __syncthreads();
  if (tid==0){
    atomicAdd(&stats[0], red[0]+red[2]+red[4]+red[6]);
    atomicAdd(&stats[1], red[1]+red[3]+red[5]+red[7]);
  }
  #pragma unroll
  for (int r=0;r<16;++r)
    X[((long)(b*512) + w0 + hl + 4*r)*1024 + h0 + wl] = s[wl][hl+4*r];
}

// BN(affine scalar)+ReLU in place; also write bf16 copy
__global__ __launch_bounds__(256) void k_bneck2(float* __restrict__ X, u16* __restrict__ Xb,
                                                const float* __restrict__ stats,
                                                const float* __restrict__ bnw, const float* __restrict__ bnb){
  long base = (long)blockIdx.x*1024 + threadIdx.x;
  float mean = stats[0] * (1.f/4194304.f);
  float var  = stats[1] * (1.f/4194304.f) - mean*mean;
  float inv  = 1.f/sqrtf(var + 1e-5f);
  float w = bnw[0], bb = bnb[0];
  #pragma unroll
  for (int j=0;j<4;++j){
    float v = X[base + j*256];
    v = fmaxf((v - mean)*inv*w + bb, 0.f);
    X[base + j*256] = v; Xb[base + j*256] = f2b(v);
  }
}

// ---------------- row LN kernels ----------------
// GLU: u = X + a*sigmoid(b), LN -> X (f32) & Xb (bf16). g is [4096][2048] bf16.
__global__ __launch_bounds__(256) void k_glu_ln(const u16* __restrict__ g, float* __restrict__ X, u16* __restrict__ Xb,
                                                const float* __restrict__ lw, const float* __restrict__ lb){
  __shared__ float sm[8];
  long r = blockIdx.x; int tid = threadIdx.x;
  float u[4]; float s1=0.f, s2=0.f;
  #pragma unroll
  for (int j=0;j<4;++j){
    int i = j*256 + tid;
    float xv = X[r*1024 + i];
    float av = b2f(g[r*2048 + i]);
    float bv = b2f(g[r*2048 + 1024 + i]);
    float t = xv + av * (1.f/(1.f + expf(-bv)));
    u[j]=t; s1+=t; s2+=t*t;
  }
  blk_sum2(s1,s2,sm);
  float m = s1*(1.f/1024.f), var = s2*(1.f/1024.f)-m*m;
  float inv = 1.f/sqrtf(var+1e-5f);
  #pragma unroll
  for (int j=0;j<4;++j){
    int i=j*256+tid;
    float o = (u[j]-m)*inv*lw[i]+lb[i];
    X[r*1024+i]=o; Xb[r*1024+i]=f2b(o);
  }
}

// residual + LN over 1024: u = X + T(bf16); -> X, Xb
__global__ __launch_bounds__(256) void k_res_ln(float* __restrict__ X, const u16* __restrict__ T, u16* __restrict__ Xb,
                                                const float* __restrict__ lw, const float* __restrict__ lb){
  __shared__ float sm[8];
  long r = blockIdx.x; int tid = threadIdx.x;
  float u[4]; float s1=0.f, s2=0.f;
  #pragma unroll
  for (int j=0;j<4;++j){
    int i = j*256 + tid;
    float t = X[r*1024 + i] + b2f(T[r*1024 + i]);
    u[j]=t; s1+=t; s2+=t*t;
  }
  blk_sum2(s1,s2,sm);
  float m = s1*(1.f/1024.f), var = s2*(1.f/1024.f)-m*m;
  float inv = 1.f/sqrtf(var+1e-5f);
  #pragma unroll
  for (int j=0;j<4;++j){
    int i=j*256+tid;
    float o = (u[j]-m)*inv*lw[i]+lb[i];
    X[r*1024+i]=o; Xb[r*1024+i]=f2b(o);
  }
}

// h = LN(hL + pad(hR)) over 4096, output bf16
__global__ __launch_bounds__(256) void k_add_ln4096(const u16* __restrict__ hL, const u16* __restrict__ hR,
                                                    u16* __restrict__ H,
                                                    const float* __restrict__ lw, const float* __restrict__ lb){
  __shared__ float sm[8];
  long r = blockIdx.x; int tid = threadIdx.x;
  float u[16]; float s1=0.f, s2=0.f;
  #pragma unroll
  for (int j=0;j<16;++j){
    int i = j*256 + tid;
    float t = b2f(hL[r*4096 + i]);
    if (j < 4) t += b2f(hR[r*1024 + i]);
    u[j]=t; s1+=t; s2+=t*t;
  }
  blk_sum2(s1,s2,sm);
  float m = s1*(1.f/4096.f), var = s2*(1.f/4096.f)-m*m;
  float inv = 1.f/sqrtf(var+1e-5f);
  #pragma unroll
  for (int j=0;j<16;++j){
    int i=j*256+tid;
    H[r*4096+i] = f2b((u[j]-m)*inv*lw[i]+lb[i]);
  }
}

// ---------------- conv path ----------------
// Abig[(b,w)][t*1024+i] = Xb[b, w+t-1, i] (zero pad)
__global__ __launch_bounds__(256) void k_gather(const u16* __restrict__ Xb, u16* __restrict__ Ab){
  int r = blockIdx.x;
  int b = r >> 9, wp = r & 511;
  for (int c = threadIdx.x; c < 384; c += 256){
    int t = c >> 7;
    int i0 = (c & 127) * 8;
    int ws_ = wp + t - 1;
    u16x8 v = {0,0,0,0,0,0,0,0};
    if (ws_ >= 0 && ws_ < 512) v = *(const u16x8*)&Xb[((long)(b*512+ws_))*1024 + i0];
    *(u16x8*)&Ab[(long)r*3072 + t*1024 + i0] = v;
  }
}

// depthwise conv k=9 over w, weights pre-transposed cdT[9][4096]
__global__ __launch_bounds__(256) void k_dw(const u16* __restrict__ H, const float* __restrict__ cdT,
                                            u16* __restrict__ HC){
  int r = blockIdx.y;
  int f0 = (blockIdx.x*256 + threadIdx.x)*8;
  int b = r>>9, wp = r&511;
  float acc[8] = {0.f,0.f,0.f,0.f,0.f,0.f,0.f,0.f};
  #pragma unroll
  for (int t=0;t<9;++t){
    int ww = wp + t - 4;
    if (ww < 0 || ww >= 512) continue;
    u16x8 hv = *(const u16x8*)&H[((long)(b*512+ww))*4096 + f0];
    f32x4_t c0 = *(const f32x4_t*)&cdT[t*4096 + f0];
    f32x4_t c1 = *(const f32x4_t*)&cdT[t*4096 + f0 + 4];
    acc[0] += b2f(hv[0]) * c0[0];
    acc[1] += b2f(hv[1]) * c0[1];
    acc[2] += b2f(hv[2]) * c0[2];
    acc[3] += b2f(hv[3]) * c0[3];
    acc[4] += b2f(hv[4]) * c1[0];
    acc[5] += b2f(hv[5]) * c1[1];
    acc[6] += b2f(hv[6]) * c1[2];
    acc[7] += b2f(hv[7]) * c1[3];
  }
  u16x8 o;
  #pragma unroll
  for (int e=0;e<8;++e) o[e] = f2b(acc[e]);
  *(u16x8*)&HC[(long)r*4096 + f0] = o;
}

// transpose v [per (b,n): 512 x 256, lda 1024] -> vT [32][256][512]
__global__ __launch_bounds__(256) void k_tv(const u16* __restrict__ V, u16* __restrict__ VT){
  __shared__ u16 s[32][33];
  int z = blockIdx.z; int b = z>>2, n = z&3;
  int d0 = blockIdx.x*32, i0 = blockIdx.y*32;
  int tx = threadIdx.x, ty = threadIdx.y;
  const u16* src = V + (long)(b*512)*1024 + n*256;
  #pragma unroll
  for (int k=0;k<4;++k)
    s[ty+8*k][tx] = src[(long)(i0+ty+8*k)*1024 + d0 + tx];
  __syncthreads();
  u16* dst = VT + (long)z*131072;
  #pragma unroll
  for (int k=0;k<4;++k)
    dst[(long)(d0+ty+8*k)*512 + i0 + tx] = s[tx][ty+8*k];
}

// ---------------- attention softmax ----------------
// scores = S/32 + |i-j|/2 * dw[n,i] + Et ; softmax over j ; P bf16
__global__ __launch_bounds__(256) void k_softmax(const float* __restrict__ S, const u16* __restrict__ Et,
                                                 const float* __restrict__ dw, u16* __restrict__ P){
  __shared__ float sm[8];
  int id = blockIdx.x;
  int i = id & 511, n = (id>>9)&3;
  long base = (long)id * 512;
  float dwv = dw[n*512 + i];
  int tid = threadIdx.x;
  float sv[2]; float mx = -1e30f;
  #pragma unroll
  for (int j2=0;j2<2;++j2){
    int j = j2*256 + tid;
    float t = S[base+j]*0.03125f + fabsf((float)(i-j))*0.5f*dwv + b2f(Et[base+j]);
    sv[j2]=t; mx = fmaxf(mx,t);
  }
  #pragma unroll
  for (int o=32;o;o>>=1) mx = fmaxf(mx, __shfl_down(mx,o,64));
  if ((tid&63)==0) sm[tid>>6]=mx;
  __syncthreads();
  mx = fmaxf(fmaxf(sm[0],sm[1]),fmaxf(sm[2],sm[3]));
  __syncthreads();
  float ev[2]; float s1=0.f;
  #pragma unroll
  for (int j2=0;j2<2;++j2){ ev[j2]=expf(sv[j2]-mx); s1+=ev[j2]; }
  #pragma unroll
  for (int o=32;o;o>>=1) s1 += __shfl_down(s1,o,64);
  if ((tid&63)==0) sm[tid>>6]=s1;
  __syncthreads();
  s1 = sm[0]+sm[1]+sm[2]+sm[3];
  float rr = 1.f/s1;
  #pragma unroll
  for (int j2=0;j2<2;++j2) P[base + j2*256 + tid] = f2b(ev[j2]*rr);
}

// ---------------- final transpose: out[b][h][w] = X[b][w][h] ----------------
__global__ __launch_bounds__(256) void k_final(const float* __restrict__ X, float* __restrict__ out){
  __shared__ float s[64][65];
  int b = blockIdx.z, h0 = blockIdx.y*64, w0 = blockIdx.x*64;
  int tid = threadIdx.x;
  int a = tid & 63, q = tid >> 6;
  #pragma unroll
  for (int r=0;r<16;++r)
    s[q+4*r][a] = X[((long)(b*512)+w0+q+4*r)*1024 + h0 + a];
  __syncthreads();
  #pragma unroll
  for (int r=0;r<16;++r)
    out[((long)(b*1024)+h0+q+4*r)*512 + w0 + a] = s[a][q+4*r];
}

// ---------------- host ----------------
extern "C" void kernel_launch(void* const* d_in, const int* in_sizes, int n_in,
                              void* d_out, int out_size, void* d_ws, size_t ws_size,
                              hipStream_t stream) {
  const float* x      = (const float*)d_in[0];
  const float* bl_w   = (const float*)d_in[1];
  const float* bn_w   = (const float*)d_in[2];
  const float* bn_b   = (const float*)d_in[3];
  const float* glu_w  = (const float*)d_in[4];
  const float* ln1_w  = (const float*)d_in[5];
  const float* ln1_b  = (const float*)d_in[6];
  const float* c1L_w  = (const float*)d_in[7];
  const float* c1R_w  = (const float*)d_in[8];
  const float* ln2_w  = (const float*)d_in[9];
  const float* ln2_b  = (const float*)d_in[10];
  const float* c2d_w  = (const float*)d_in[11];
  const float* c2p_w  = (const float*)d_in[12];
  const float* ln3_w  = (const float*)d_in[13];
  const float* ln3_b  = (const float*)d_in[14];
  const float* q_w    = (const float*)d_in[15];
  const float* k_w    = (const float*)d_in[16];
  const float* v_w    = (const float*)d_in[17];
  const float* o_w    = (const float*)d_in[18];
  const float* er     = (const float*)d_in[19];
  const float* dist_w = (const float*)d_in[20];
  const float* ln4_w  = (const float*)d_in[21];
  const float* ln4_b  = (const float*)d_in[22];
  const float* c3_w   = (const float*)d_in[23];
  const float* c4_w   = (const float*)d_in[24];
  const float* ln5_w  = (const float*)d_in[25];
  const float* ln5_b  = (const float*)d_in[26];

  char* ws = (char*)d_ws;
  size_t off = 0;
  auto alloc = [&](size_t n){ size_t o = off; off = (off + n + 255) & ~(size_t)255; return o; };

  size_t o_wglu = alloc(2048ull*1024*2);
  size_t o_wc1L = alloc(4096ull*1024*2);
  size_t o_wc1R = alloc(1024ull*3072*2);
  size_t o_wc2p = alloc(1024ull*4096*2);
  size_t o_wq   = alloc(1024ull*1024*2);
  size_t o_wk   = alloc(1024ull*1024*2);
  size_t o_wv   = alloc(1024ull*1024*2);
  size_t o_wo   = alloc(1024ull*1024*2);
  size_t o_wert = alloc(512ull*256*2);
  size_t o_wc3  = alloc(4096ull*1024*2);
  size_t o_wc4  = alloc(1024ull*4096*2);
  size_t o_cdt  = alloc(9ull*4096*4);
  size_t o_X    = alloc(4096ull*1024*4);
  size_t o_Xb   = alloc(4096ull*1024*2);
  size_t o_A1   = alloc(33554432);
  size_t o_A2   = alloc(33554432);
  size_t o_A3   = alloc(33554432);
  size_t o_A4   = alloc(16777216);
  size_t o_st   = alloc(256);
  (void)ws_size; (void)n_in; (void)in_sizes; (void)out_size;

  u16* WGLU = (u16*)(ws+o_wglu); u16* WC1L = (u16*)(ws+o_wc1L); u16* WC1R = (u16*)(ws+o_wc1R);
  u16* WC2P = (u16*)(ws+o_wc2p); u16* WQ = (u16*)(ws+o_wq); u16* WK = (u16*)(ws+o_wk);
  u16* WV = (u16*)(ws+o_wv); u16* WO = (u16*)(ws+o_wo); u16* WERT = (u16*)(ws+o_wert);
  u16* WC3 = (u16*)(ws+o_wc3); u16* WC4 = (u16*)(ws+o_wc4);
  float* CDT = (float*)(ws+o_cdt);
  float* X = (float*)(ws+o_X); u16* Xb = (u16*)(ws+o_Xb);
  u16* A1 = (u16*)(ws+o_A1); u16* A2 = (u16*)(ws+o_A2);
  u16* A3 = (u16*)(ws+o_A3); u16* A4 = (u16*)(ws+o_A4);
  float* stats = (float*)(ws+o_st);

  auto GEMM = [&](int epi, const u16* A, int lda, long aS1, long aS2,
                  const u16* B, int ldb, long bS1, long bS2,
                  void* C, int ldc, long cS1, long cS2,
                  int M, int N, int K, int zdiv, int nz){
    dim3 grid(N/128, M/128, nz);
    if (epi==0)      gemm_k<0><<<grid,256,0,stream>>>(A,lda,aS1,aS2,B,ldb,bS1,bS2,C,ldc,cS1,cS2,K,zdiv);
    else if (epi==1) gemm_k<1><<<grid,256,0,stream>>>(A,lda,aS1,aS2,B,ldb,bS1,bS2,C,ldc,cS1,cS2,K,zdiv);
    else             gemm_k<2><<<grid,256,0,stream>>>(A,lda,aS1,aS2,B,ldb,bS1,bS2,C,ldc,cS1,cS2,K,zdiv);
  };

  // ---- weight prep ----
  k_zero<<<1,64,0,stream>>>(stats);
  k_tcvt<<<dim3(64,32),dim3(32,8),0,stream>>>(glu_w, WGLU, 1024, 2048);
  k_tcvt<<<dim3(128,32),dim3(32,8),0,stream>>>(c1L_w, WC1L, 1024, 4096);
  k_c1rp<<<dim3(1024,12),256,0,stream>>>(c1R_w, WC1R);
  k_cvt<<<4096,256,0,stream>>>(c2p_w, WC2P);
  k_cdt<<<144,256,0,stream>>>(c2d_w, CDT);
  k_tcvt<<<dim3(32,32),dim3(32,8),0,stream>>>(q_w, WQ, 1024, 1024);
  k_tcvt<<<dim3(32,32),dim3(32,8),0,stream>>>(k_w, WK, 1024, 1024);
  k_tcvt<<<dim3(32,32),dim3(32,8),0,stream>>>(v_w, WV, 1024, 1024);
  k_tcvt<<<dim3(32,32),dim3(32,8),0,stream>>>(o_w, WO, 1024, 1024);
  k_tcvt<<<dim3(16,8),dim3(32,8),0,stream>>>(er, WERT, 256, 512);
  k_tcvt<<<dim3(128,32),dim3(32,8),0,stream>>>(c3_w, WC3, 1024, 4096);
  k_tcvt<<<dim3(32,128),dim3(32,8),0,stream>>>(c4_w, WC4, 4096, 1024);

  // ---- bottleneck + BN + ReLU ----
  k_bneck1<<<dim3(8,16,8),256,0,stream>>>(x, bl_w, X, stats);
  k_bneck2<<<4096,256,0,stream>>>(X, Xb, stats, bn_w, bn_b);

  // ---- GLU + LN1 ----
  GEMM(0, Xb,1024,0,0, WGLU,1024,0,0, A1,2048,0,0, 4096,2048,1024, 1,1);
  k_glu_ln<<<4096,256,0,stream>>>(A1, X, Xb, ln1_w, ln1_b);

  // ---- dual branch + LN2 ----
  k_gather<<<4096,256,0,stream>>>(Xb, A3);                         // Abig [4096][3072]
  GEMM(1, Xb,1024,0,0, WC1L,1024,0,0, A1,4096,0,0, 4096,4096,1024, 1,1);   // hL
  GEMM(1, A3,3072,0,0, WC1R,3072,0,0, A4,1024,0,0, 4096,1024,3072, 1,1);   // hR
  k_add_ln4096<<<4096,256,0,stream>>>(A1, A4, A2, ln2_w, ln2_b);   // h -> A2

  // ---- depthwise + pointwise + LN3 ----
  k_dw<<<dim3(2,4096),256,0,stream>>>(A2, CDT, A1);                // hc -> A1
  GEMM(0, A1,4096,0,0, WC2P,4096,0,0, A4,1024,0,0, 4096,1024,4096, 1,1);   // pw -> A4
  k_res_ln<<<4096,256,0,stream>>>(X, A4, Xb, ln3_w, ln3_b);

  // ---- attention ----
  u16* Aq = A1;               // [4096][1024]
  u16* Ak = A1 + 4194304;
  u16* Av = A1 + 8388608;
  GEMM(0, Xb,1024,0,0, WQ,1024,0,0, Aq,1024,0,0, 4096,1024,1024, 1,1);
  GEMM(0, Xb,1024,0,0, WK,1024,0,0, Ak,1024,0,0, 4096,1024,1024, 1,1);
  GEMM(0, Xb,1024,0,0, WV,1024,0,0, Av,1024,0,0, 4096,1024,1024, 1,1);
  u16* VT = A2;               // [32][256][512]
  k_tv<<<dim3(8,16,32),dim3(32,8),0,stream>>>(Av, VT);
  float* Sf = (float*)A3;     // [8][4][512][512] f32
  GEMM(2, Aq,1024,524288,256, Ak,1024,524288,256, Sf,512,1048576,262144, 512,512,256, 4,32);
  u16* EtB = (u16*)(ws + o_A2 + 8388608);   // [8][4][512][512] bf16
  GEMM(0, WERT,256,0,0, Aq,1024,524288,256, EtB,512,1048576,262144, 512,512,256, 4,32);
  u16* P = A4;                // probs bf16
  k_softmax<<<16384,256,0,stream>>>(Sf, EtB, dist_w, P);
  u16* Ov = A1;               // [4096][1024] (q/k/v dead)
  GEMM(0, P,512,1048576,262144, VT,512,524288,131072, Ov,1024,524288,256, 512,256,512, 4,32);
  u16* AOp = A3;              // o-proj out
  GEMM(0, Ov,1024,0,0, WO,1024,0,0, AOp,1024,0,0, 4096,1024,1024, 1,1);
  k_res_ln<<<4096,256,0,stream>>>(X, AOp, Xb, ln4_w, ln4_b);

  // ---- FFN + LN5 ----
  GEMM(1, Xb,1024,0,0, WC3,1024,0,0, A1,4096,0,0, 4096,4096,1024, 1,1);
  GEMM(0, A1,4096,0,0, WC4,4096,0,0, A4,1024,0,0, 4096,1024,4096, 1,1);
  k_res_ln<<<4096,256,0,stream>>>(X, A4, Xb, ln5_w, ln5_b);

  // ---- output ----
  k_final<<<dim3(8,16,8),256,0,stream>>>(X, (float*)d_out);
}

// Round 4
// 1101.873 us; speedup vs baseline: 1.3742x; 1.1812x over previous
//
#include <hip/hip_runtime.h>
#include <stdint.h>

typedef unsigned short u16;
typedef __bf16 bf16x8_t __attribute__((ext_vector_type(8)));
typedef float f32x4_t __attribute__((ext_vector_type(4)));
typedef u16 u16x8 __attribute__((ext_vector_type(8)));

#define DEVINL static __device__ __forceinline__

DEVINL float b2f(u16 h){ union{unsigned u; float f;} v; v.u=((unsigned)h)<<16; return v.f; }
DEVINL u16 f2b(float f){ union{float f; unsigned u;} v; v.f=f; unsigned u=v.u; u += 0x7fffu + ((u>>16)&1u); return (u16)(u>>16); }

DEVINL void gload16(const void* g, void* lds){
  __builtin_amdgcn_global_load_lds((__attribute__((address_space(1))) void*)(void*)g,
                                   (__attribute__((address_space(3))) void*)lds, 16, 0, 0);
}

// block-wide (256 thr) sum of two floats; sm = shared float[8]
DEVINL void blk_sum2(float& a, float& b, float* sm){
  #pragma unroll
  for (int o=32;o;o>>=1){ a += __shfl_down(a,o,64); b += __shfl_down(b,o,64); }
  int tid = threadIdx.x;
  if ((tid&63)==0){ sm[(tid>>6)*2]=a; sm[(tid>>6)*2+1]=b; }
  __syncthreads();
  a = sm[0]+sm[2]+sm[4]+sm[6];
  b = sm[1]+sm[3]+sm[5]+sm[7];
  __syncthreads();
}

// ---------------- GEMM: C[M,N] = A[M,K] @ B^T, B stored [N][K] (both bf16/u16) ----------------
// BM=BN=128, BK=32, 256 threads = 4 waves in 2x2, each wave 64x64 (4x4 16x16x32 MFMA frags).
// XCD-aware bijective tile swizzle (T1, m204 formula) on the (y,x)-flattened tile id.
template<int EPI>  // 0: bf16 store, 1: bf16 relu store, 2: f32 store
__global__ __launch_bounds__(256) void gemm_k(
    const u16* __restrict__ A, int lda, long aS1, long aS2,
    const u16* __restrict__ B, int ldb, long bS1, long bS2,
    void* __restrict__ Cv, int ldc, long cS1, long cS2,
    int K, int zdiv)
{
  __shared__ u16 sA[128*32];
  __shared__ u16 sB[128*32];
  const int tid = threadIdx.x;
  const int w = tid >> 6, l = tid & 63;
  const int z = blockIdx.z; const int z1 = z / zdiv, z2 = z % zdiv;
  const u16* Ab = A + z1*aS1 + z2*aS2;
  const u16* Bb = B + z1*bS1 + z2*bS2;

  // XCD bijective swizzle within the z-plane
  const int gx = gridDim.x;
  const int nwg = gx * gridDim.y;
  const int orig = blockIdx.y*gx + blockIdx.x;
  const int qq = nwg >> 3, rr8 = nwg & 7;
  const int xcd = orig & 7, idx8 = orig >> 3;
  const int wgid = (xcd < rr8 ? xcd*(qq+1) : rr8*(qq+1) + (xcd-rr8)*qq) + idx8;
  const int rowB = (wgid / gx) * 128, colB = (wgid % gx) * 128;

  const int sr = w*32 + (l>>2);      // staging row within tile
  const int so = (l&3)*8;            // staging k-offset (elements)
  const u16* gA0 = Ab + (long)(rowB + sr)*lda + so;
  const u16* gA1 = gA0 + (long)16*lda;
  const u16* gB0 = Bb + (long)(colB + sr)*ldb + so;
  const u16* gB1 = gB0 + (long)16*ldb;
  u16* lA0 = sA + w*1024; u16* lA1 = lA0 + 512;   // wave-uniform LDS dests
  u16* lB0 = sB + w*1024; u16* lB1 = lB0 + 512;

  const int lrow = l & 15, lg = l >> 4;
  const int wrow = w & 1, wcol = w >> 1;

  f32x4_t zz = {0.f,0.f,0.f,0.f};
  f32x4_t acc[4][4];
  #pragma unroll
  for (int mi=0; mi<4; ++mi)
    #pragma unroll
    for (int ni=0; ni<4; ++ni) acc[mi][ni] = zz;

  for (int k0 = 0; k0 < K; k0 += 32) {
    __syncthreads();
    gload16(gA0 + k0, lA0);
    gload16(gA1 + k0, lA1);
    gload16(gB0 + k0, lB0);
    gload16(gB1 + k0, lB1);
    __syncthreads();
    bf16x8_t af[4], bfr[4];
    #pragma unroll
    for (int mi=0; mi<4; ++mi)
      af[mi] = *(const bf16x8_t*)&sA[(wrow*64 + mi*16 + lrow)*32 + lg*8];
    #pragma unroll
    for (int ni=0; ni<4; ++ni)
      bfr[ni] = *(const bf16x8_t*)&sB[(wcol*64 + ni*16 + lrow)*32 + lg*8];
    #pragma unroll
    for (int mi=0; mi<4; ++mi)
      #pragma unroll
      for (int ni=0; ni<4; ++ni)
        acc[mi][ni] = __builtin_amdgcn_mfma_f32_16x16x32_bf16(af[mi], bfr[ni], acc[mi][ni], 0,0,0);
  }

  const long cb = z1*cS1 + z2*cS2;
  #pragma unroll
  for (int mi=0; mi<4; ++mi)
  #pragma unroll
  for (int ni=0; ni<4; ++ni)
  #pragma unroll
  for (int j=0; j<4; ++j) {
    const long rr = rowB + wrow*64 + mi*16 + lg*4 + j;
    const long cc = colB + wcol*64 + ni*16 + lrow;
    float v = acc[mi][ni][j];
    if (EPI == 2) ((float*)Cv)[cb + rr*(long)ldc + cc] = v;
    else {
      if (EPI == 1) v = fmaxf(v, 0.f);
      ((u16*)Cv)[cb + rr*(long)ldc + cc] = f2b(v);
    }
  }
}

// ---------------- weight prep ----------------
// transpose+convert: src f32 [R][Cc] -> dst bf16 [Cc][R]
__global__ __launch_bounds__(256) void k_tcvt(const float* __restrict__ src, u16* __restrict__ dst, int R, int Cc){
  __shared__ float s[32][33];
  int c0 = blockIdx.x*32, r0 = blockIdx.y*32;
  int tx = threadIdx.x, ty = threadIdx.y;
  #pragma unroll
  for (int k=0;k<4;++k)
    s[ty+8*k][tx] = src[(long)(r0+ty+8*k)*Cc + c0+tx];
  __syncthreads();
  #pragma unroll
  for (int k=0;k<4;++k)
    dst[(long)(c0+ty+8*k)*R + r0+tx] = f2b(s[tx][ty+8*k]);
}

// elementwise convert f32->bf16 (grid*1024 elements)
__global__ __launch_bounds__(256) void k_cvt(const float* __restrict__ src, u16* __restrict__ dst){
  long base = (long)blockIdx.x*1024 + threadIdx.x;
  #pragma unroll
  for (int j=0;j<4;++j) dst[base + j*256] = f2b(src[base + j*256]);
}

// c1R [O=1024][I=1024][T=3] -> dst[o][t*1024+i] bf16   grid(1024,12)
__global__ __launch_bounds__(256) void k_c1rp(const float* __restrict__ src, u16* __restrict__ dst){
  int o = blockIdx.x; int kk = blockIdx.y*256 + threadIdx.x;
  int i = kk & 1023, t = kk >> 10;
  dst[(long)o*3072 + kk] = f2b(src[(long)o*3072 + i*3 + t]);
}

// depthwise weight transpose: src [4096][9] -> dst [9][4096] f32.  grid(144)
__global__ __launch_bounds__(256) void k_cdt(const float* __restrict__ src, float* __restrict__ dst){
  int idx = blockIdx.x*256 + threadIdx.x;   // 0..36863
  int t = idx >> 12, f = idx & 4095;
  dst[idx] = src[f*9 + t];
}

__global__ void k_zero(float* p){ if (threadIdx.x < 2) p[threadIdx.x] = 0.f; }

// ---------------- bottleneck ----------------
__global__ __launch_bounds__(256) void k_bneck1(const float* __restrict__ x, const float* __restrict__ blw,
                                                float* __restrict__ X, float* __restrict__ stats){
  __shared__ float s[64][65];
  __shared__ float red[8];
  int b = blockIdx.z, h0 = blockIdx.y*64, w0 = blockIdx.x*64;
  int tid = threadIdx.x;
  int wl = tid & 63, hl = tid >> 6;
  float yacc[16];
  #pragma unroll
  for (int r=0;r<16;++r) yacc[r]=0.f;
  for (int c=0;c<16;++c){
    float wc = blw[c];
    const float* xp = x + (((long)(b*16 + c)*1024 + h0)*512 + w0);
    #pragma unroll
    for (int r=0;r<16;++r)
      yacc[r] += xp[(hl + 4*r)*512 + wl] * wc;
  }
  float s1=0.f, s2=0.f;
  #pragma unroll
  for (int r=0;r<16;++r){ s1+=yacc[r]; s2+=yacc[r]*yacc[r]; }
  #pragma unroll
  for (int o=32;o;o>>=1){ s1+=__shfl_down(s1,o,64); s2+=__shfl_down(s2,o,64); }
  if ((tid&63)==0){ red[(tid>>6)*2]=s1; red[(tid>>6)*2+1]=s2; }
  #pragma unroll
  for (int r=0;r<16;++r) s[hl+4*r][wl] = yacc[r];
  __syncthreads();
  if (tid==0){
    atomicAdd(&stats[0], red[0]+red[2]+red[4]+red[6]);
    atomicAdd(&stats[1], red[1]+red[3]+red[5]+red[7]);
  }
  #pragma unroll
  for (int r=0;r<16;++r)
    X[((long)(b*512) + w0 + hl + 4*r)*1024 + h0 + wl] = s[wl][hl+4*r];
}

__global__ __launch_bounds__(256) void k_bneck2(float* __restrict__ X, u16* __restrict__ Xb,
                                                const float* __restrict__ stats,
                                                const float* __restrict__ bnw, const float* __restrict__ bnb){
  long base = (long)blockIdx.x*1024 + threadIdx.x;
  float mean = stats[0] * (1.f/4194304.f);
  float var  = stats[1] * (1.f/4194304.f) - mean*mean;
  float inv  = 1.f/sqrtf(var + 1e-5f);
  float w = bnw[0], bb = bnb[0];
  #pragma unroll
  for (int j=0;j<4;++j){
    float v = X[base + j*256];
    v = fmaxf((v - mean)*inv*w + bb, 0.f);
    X[base + j*256] = v; Xb[base + j*256] = f2b(v);
  }
}

// ---------------- row LN kernels ----------------
__global__ __launch_bounds__(256) void k_glu_ln(const u16* __restrict__ g, float* __restrict__ X, u16* __restrict__ Xb,
                                                const float* __restrict__ lw, const float* __restrict__ lb){
  __shared__ float sm[8];
  long r = blockIdx.x; int tid = threadIdx.x;
  float u[4]; float s1=0.f, s2=0.f;
  #pragma unroll
  for (int j=0;j<4;++j){
    int i = j*256 + tid;
    float xv = X[r*1024 + i];
    float av = b2f(g[r*2048 + i]);
    float bv = b2f(g[r*2048 + 1024 + i]);
    float t = xv + av * (1.f/(1.f + expf(-bv)));
    u[j]=t; s1+=t; s2+=t*t;
  }
  blk_sum2(s1,s2,sm);
  float m = s1*(1.f/1024.f), var = s2*(1.f/1024.f)-m*m;
  float inv = 1.f/sqrtf(var+1e-5f);
  #pragma unroll
  for (int j=0;j<4;++j){
    int i=j*256+tid;
    float o = (u[j]-m)*inv*lw[i]+lb[i];
    X[r*1024+i]=o; Xb[r*1024+i]=f2b(o);
  }
}

// residual + LN over 1024, residual from TWO f32 split-K partials: u = X + P[r]+P[r+4M]
__global__ __launch_bounds__(256) void k_res_ln2(float* __restrict__ X, const float* __restrict__ P, u16* __restrict__ Xb,
                                                 const float* __restrict__ lw, const float* __restrict__ lb){
  __shared__ float sm[8];
  long r = blockIdx.x; int tid = threadIdx.x;
  float u[4]; float s1=0.f, s2=0.f;
  #pragma unroll
  for (int j=0;j<4;++j){
    int i = j*256 + tid;
    float t = X[r*1024 + i] + P[r*1024 + i] + P[4194304 + r*1024 + i];
    u[j]=t; s1+=t; s2+=t*t;
  }
  blk_sum2(s1,s2,sm);
  float m = s1*(1.f/1024.f), var = s2*(1.f/1024.f)-m*m;
  float inv = 1.f/sqrtf(var+1e-5f);
  #pragma unroll
  for (int j=0;j<4;++j){
    int i=j*256+tid;
    float o = (u[j]-m)*inv*lw[i]+lb[i];
    X[r*1024+i]=o; Xb[r*1024+i]=f2b(o);
  }
}

// h = LN(hL + pad(relu(P1+P2))) over 4096, output bf16; P f32 split-K partials [4096][1024] x2
__global__ __launch_bounds__(256) void k_add_ln4096_2(const u16* __restrict__ hL, const float* __restrict__ P,
                                                      u16* __restrict__ H,
                                                      const float* __restrict__ lw, const float* __restrict__ lb){
  __shared__ float sm[8];
  long r = blockIdx.x; int tid = threadIdx.x;
  float u[16]; float s1=0.f, s2=0.f;
  #pragma unroll
  for (int j=0;j<16;++j){
    int i = j*256 + tid;
    float t = b2f(hL[r*4096 + i]);
    if (j < 4) t += fmaxf(P[r*1024 + i] + P[4194304 + r*1024 + i], 0.f);
    u[j]=t; s1+=t; s2+=t*t;
  }
  blk_sum2(s1,s2,sm);
  float m = s1*(1.f/4096.f), var = s2*(1.f/4096.f)-m*m;
  float inv = 1.f/sqrtf(var+1e-5f);
  #pragma unroll
  for (int j=0;j<16;++j){
    int i=j*256+tid;
    H[r*4096+i] = f2b((u[j]-m)*inv*lw[i]+lb[i]);
  }
}

// ---------------- conv path ----------------
__global__ __launch_bounds__(256) void k_gather(const u16* __restrict__ Xb, u16* __restrict__ Ab){
  int r = blockIdx.x;
  int b = r >> 9, wp = r & 511;
  for (int c = threadIdx.x; c < 384; c += 256){
    int t = c >> 7;
    int i0 = (c & 127) * 8;
    int ws_ = wp + t - 1;
    u16x8 v = {0,0,0,0,0,0,0,0};
    if (ws_ >= 0 && ws_ < 512) v = *(const u16x8*)&Xb[((long)(b*512+ws_))*1024 + i0];
    *(u16x8*)&Ab[(long)r*3072 + t*1024 + i0] = v;
  }
}

// depthwise conv k=9 over w, weights pre-transposed cdT[9][4096]
__global__ __launch_bounds__(256) void k_dw(const u16* __restrict__ H, const float* __restrict__ cdT,
                                            u16* __restrict__ HC){
  int r = blockIdx.y;
  int f0 = (blockIdx.x*256 + threadIdx.x)*8;
  int b = r>>9, wp = r&511;
  float acc[8] = {0.f,0.f,0.f,0.f,0.f,0.f,0.f,0.f};
  #pragma unroll
  for (int t=0;t<9;++t){
    int ww = wp + t - 4;
    if (ww < 0 || ww >= 512) continue;
    u16x8 hv = *(const u16x8*)&H[((long)(b*512+ww))*4096 + f0];
    f32x4_t c0 = *(const f32x4_t*)&cdT[t*4096 + f0];
    f32x4_t c1 = *(const f32x4_t*)&cdT[t*4096 + f0 + 4];
    acc[0] += b2f(hv[0]) * c0[0];
    acc[1] += b2f(hv[1]) * c0[1];
    acc[2] += b2f(hv[2]) * c0[2];
    acc[3] += b2f(hv[3]) * c0[3];
    acc[4] += b2f(hv[4]) * c1[0];
    acc[5] += b2f(hv[5]) * c1[1];
    acc[6] += b2f(hv[6]) * c1[2];
    acc[7] += b2f(hv[7]) * c1[3];
  }
  u16x8 o;
  #pragma unroll
  for (int e=0;e<8;++e) o[e] = f2b(acc[e]);
  *(u16x8*)&HC[(long)r*4096 + f0] = o;
}

// transpose v [per (b,n): 512 x 256, row stride lda] -> vT [32][256][512]
__global__ __launch_bounds__(256) void k_tv(const u16* __restrict__ V, u16* __restrict__ VT, int lda){
  __shared__ u16 s[32][33];
  int z = blockIdx.z; int b = z>>2, n = z&3;
  int d0 = blockIdx.x*32, i0 = blockIdx.y*32;
  int tx = threadIdx.x, ty = threadIdx.y;
  const u16* src = V + (long)(b*512)*lda + n*256;
  #pragma unroll
  for (int k=0;k<4;++k)
    s[ty+8*k][tx] = src[(long)(i0+ty+8*k)*lda + d0 + tx];
  __syncthreads();
  u16* dst = VT + (long)z*131072;
  #pragma unroll
  for (int k=0;k<4;++k)
    dst[(long)(d0+ty+8*k)*512 + i0 + tx] = s[tx][ty+8*k];
}

// ---------------- attention softmax ----------------
__global__ __launch_bounds__(256) void k_softmax(const float* __restrict__ S, const u16* __restrict__ Et,
                                                 const float* __restrict__ dw, u16* __restrict__ P){
  __shared__ float sm[8];
  int id = blockIdx.x;
  int i = id & 511, n = (id>>9)&3;
  long base = (long)id * 512;
  float dwv = dw[n*512 + i];
  int tid = threadIdx.x;
  float sv[2]; float mx = -1e30f;
  #pragma unroll
  for (int j2=0;j2<2;++j2){
    int j = j2*256 + tid;
    float t = S[base+j]*0.03125f + fabsf((float)(i-j))*0.5f*dwv + b2f(Et[base+j]);
    sv[j2]=t; mx = fmaxf(mx,t);
  }
  #pragma unroll
  for (int o=32;o;o>>=1) mx = fmaxf(mx, __shfl_down(mx,o,64));
  if ((tid&63)==0) sm[tid>>6]=mx;
  __syncthreads();
  mx = fmaxf(fmaxf(sm[0],sm[1]),fmaxf(sm[2],sm[3]));
  __syncthreads();
  float ev[2]; float s1=0.f;
  #pragma unroll
  for (int j2=0;j2<2;++j2){ ev[j2]=expf(sv[j2]-mx); s1+=ev[j2]; }
  #pragma unroll
  for (int o=32;o;o>>=1) s1 += __shfl_down(s1,o,64);
  if ((tid&63)==0) sm[tid>>6]=s1;
  __syncthreads();
  s1 = sm[0]+sm[1]+sm[2]+sm[3];
  float rr = 1.f/s1;
  #pragma unroll
  for (int j2=0;j2<2;++j2) P[base + j2*256 + tid] = f2b(ev[j2]*rr);
}

// ---------------- final transpose: out[b][h][w] = X[b][w][h] ----------------
__global__ __launch_bounds__(256) void k_final(const float* __restrict__ X, float* __restrict__ out){
  __shared__ float s[64][65];
  int b = blockIdx.z, h0 = blockIdx.y*64, w0 = blockIdx.x*64;
  int tid = threadIdx.x;
  int a = tid & 63, q = tid >> 6;
  #pragma unroll
  for (int r=0;r<16;++r)
    s[q+4*r][a] = X[((long)(b*512)+w0+q+4*r)*1024 + h0 + a];
  __syncthreads();
  #pragma unroll
  for (int r=0;r<16;++r)
    out[((long)(b*1024)+h0+q+4*r)*512 + w0 + a] = s[a][q+4*r];
}

// ---------------- host ----------------
extern "C" void kernel_launch(void* const* d_in, const int* in_sizes, int n_in,
                              void* d_out, int out_size, void* d_ws, size_t ws_size,
                              hipStream_t stream) {
  const float* x      = (const float*)d_in[0];
  const float* bl_w   = (const float*)d_in[1];
  const float* bn_w   = (const float*)d_in[2];
  const float* bn_b   = (const float*)d_in[3];
  const float* glu_w  = (const float*)d_in[4];
  const float* ln1_w  = (const float*)d_in[5];
  const float* ln1_b  = (const float*)d_in[6];
  const float* c1L_w  = (const float*)d_in[7];
  const float* c1R_w  = (const float*)d_in[8];
  const float* ln2_w  = (const float*)d_in[9];
  const float* ln2_b  = (const float*)d_in[10];
  const float* c2d_w  = (const float*)d_in[11];
  const float* c2p_w  = (const float*)d_in[12];
  const float* ln3_w  = (const float*)d_in[13];
  const float* ln3_b  = (const float*)d_in[14];
  const float* q_w    = (const float*)d_in[15];
  const float* k_w    = (const float*)d_in[16];
  const float* v_w    = (const float*)d_in[17];
  const float* o_w    = (const float*)d_in[18];
  const float* er     = (const float*)d_in[19];
  const float* dist_w = (const float*)d_in[20];
  const float* ln4_w  = (const float*)d_in[21];
  const float* ln4_b  = (const float*)d_in[22];
  const float* c3_w   = (const float*)d_in[23];
  const float* c4_w   = (const float*)d_in[24];
  const float* ln5_w  = (const float*)d_in[25];
  const float* ln5_b  = (const float*)d_in[26];

  char* ws = (char*)d_ws;
  size_t off = 0;
  auto alloc = [&](size_t n){ size_t o = off; off = (off + n + 255) & ~(size_t)255; return o; };

  size_t o_wglu = alloc(2048ull*1024*2);
  size_t o_wc1L = alloc(4096ull*1024*2);
  size_t o_wc1R = alloc(1024ull*3072*2);
  size_t o_wc2p = alloc(1024ull*4096*2);
  size_t o_wqkv = alloc(3072ull*1024*2);   // fused Q|K|V weights [3072][1024]
  size_t o_wo   = alloc(1024ull*1024*2);
  size_t o_wert = alloc(512ull*256*2);
  size_t o_wc3  = alloc(4096ull*1024*2);
  size_t o_wc4  = alloc(1024ull*4096*2);
  size_t o_cdt  = alloc(9ull*4096*4);
  size_t o_X    = alloc(4096ull*1024*4);
  size_t o_Xb   = alloc(4096ull*1024*2);
  size_t o_A1   = alloc(33554432);
  size_t o_A2   = alloc(33554432);
  size_t o_A3   = alloc(33554432);
  size_t o_A4   = alloc(16777216);
  size_t o_A5   = alloc(33554432);         // f32 split-K partials (2 x 16 MiB)
  size_t o_st   = alloc(256);
  (void)ws_size; (void)n_in; (void)in_sizes; (void)out_size;

  u16* WGLU = (u16*)(ws+o_wglu); u16* WC1L = (u16*)(ws+o_wc1L); u16* WC1R = (u16*)(ws+o_wc1R);
  u16* WC2P = (u16*)(ws+o_wc2p); u16* WQKV = (u16*)(ws+o_wqkv);
  u16* WO = (u16*)(ws+o_wo); u16* WERT = (u16*)(ws+o_wert);
  u16* WC3 = (u16*)(ws+o_wc3); u16* WC4 = (u16*)(ws+o_wc4);
  float* CDT = (float*)(ws+o_cdt);
  float* X = (float*)(ws+o_X); u16* Xb = (u16*)(ws+o_Xb);
  u16* A1 = (u16*)(ws+o_A1); u16* A2 = (u16*)(ws+o_A2);
  u16* A3 = (u16*)(ws+o_A3); u16* A4 = (u16*)(ws+o_A4);
  float* A5 = (float*)(ws+o_A5);
  float* stats = (float*)(ws+o_st);

  auto GEMM = [&](int epi, const u16* A, int lda, long aS1, long aS2,
                  const u16* B, int ldb, long bS1, long bS2,
                  void* C, int ldc, long cS1, long cS2,
                  int M, int N, int K, int zdiv, int nz){
    dim3 grid(N/128, M/128, nz);
    if (epi==0)      gemm_k<0><<<grid,256,0,stream>>>(A,lda,aS1,aS2,B,ldb,bS1,bS2,C,ldc,cS1,cS2,K,zdiv);
    else if (epi==1) gemm_k<1><<<grid,256,0,stream>>>(A,lda,aS1,aS2,B,ldb,bS1,bS2,C,ldc,cS1,cS2,K,zdiv);
    else             gemm_k<2><<<grid,256,0,stream>>>(A,lda,aS1,aS2,B,ldb,bS1,bS2,C,ldc,cS1,cS2,K,zdiv);
  };

  // ---- weight prep ----
  k_zero<<<1,64,0,stream>>>(stats);
  k_tcvt<<<dim3(64,32),dim3(32,8),0,stream>>>(glu_w, WGLU, 1024, 2048);
  k_tcvt<<<dim3(128,32),dim3(32,8),0,stream>>>(c1L_w, WC1L, 1024, 4096);
  k_c1rp<<<dim3(1024,12),256,0,stream>>>(c1R_w, WC1R);
  k_cvt<<<4096,256,0,stream>>>(c2p_w, WC2P);
  k_cdt<<<144,256,0,stream>>>(c2d_w, CDT);
  k_tcvt<<<dim3(32,32),dim3(32,8),0,stream>>>(q_w, WQKV, 1024, 1024);
  k_tcvt<<<dim3(32,32),dim3(32,8),0,stream>>>(k_w, WQKV + 1048576, 1024, 1024);
  k_tcvt<<<dim3(32,32),dim3(32,8),0,stream>>>(v_w, WQKV + 2097152, 1024, 1024);
  k_tcvt<<<dim3(32,32),dim3(32,8),0,stream>>>(o_w, WO, 1024, 1024);
  k_tcvt<<<dim3(16,8),dim3(32,8),0,stream>>>(er, WERT, 256, 512);
  k_tcvt<<<dim3(128,32),dim3(32,8),0,stream>>>(c3_w, WC3, 1024, 4096);
  k_tcvt<<<dim3(32,128),dim3(32,8),0,stream>>>(c4_w, WC4, 4096, 1024);

  // ---- bottleneck + BN + ReLU ----
  k_bneck1<<<dim3(8,16,8),256,0,stream>>>(x, bl_w, X, stats);
  k_bneck2<<<4096,256,0,stream>>>(X, Xb, stats, bn_w, bn_b);

  // ---- GLU + LN1 ----
  GEMM(0, Xb,1024,0,0, WGLU,1024,0,0, A1,2048,0,0, 4096,2048,1024, 1,1);
  k_glu_ln<<<4096,256,0,stream>>>(A1, X, Xb, ln1_w, ln1_b);

  // ---- dual branch + LN2 ----
  k_gather<<<4096,256,0,stream>>>(Xb, A3);                         // Abig [4096][3072]
  GEMM(1, Xb,1024,0,0, WC1L,1024,0,0, A1,4096,0,0, 4096,4096,1024, 1,1);           // hL -> A1
  GEMM(2, A3,3072,1536,0, WC1R,3072,1536,0, A5,1024,4194304,0, 4096,1024,1536, 1,2); // hR split-K -> A5
  k_add_ln4096_2<<<4096,256,0,stream>>>(A1, A5, A2, ln2_w, ln2_b); // h -> A2

  // ---- depthwise + pointwise + LN3 ----
  k_dw<<<dim3(2,4096),256,0,stream>>>(A2, CDT, A1);                // hc -> A1
  GEMM(2, A1,4096,2048,0, WC2P,4096,2048,0, A5,1024,4194304,0, 4096,1024,2048, 1,2); // pw split-K
  k_res_ln2<<<4096,256,0,stream>>>(X, A5, Xb, ln3_w, ln3_b);

  // ---- attention ----
  u16* AQKV = A1;             // [4096][3072]: q | k | v column blocks
  GEMM(0, Xb,1024,0,0, WQKV,1024,0,0, AQKV,3072,0,0, 4096,3072,1024, 1,1);
  const u16* Aq = AQKV;
  const u16* Ak = AQKV + 1024;
  const u16* Av = AQKV + 2048;
  u16* VT = A2;               // [32][256][512]
  k_tv<<<dim3(8,16,32),dim3(32,8),0,stream>>>(Av, VT, 3072);
  float* Sf = (float*)A3;     // [8][4][512][512] f32
  GEMM(2, Aq,3072,1572864,256, Ak,3072,1572864,256, Sf,512,1048576,262144, 512,512,256, 4,32);
  u16* EtB = (u16*)(ws + o_A2 + 8388608);   // [8][4][512][512] bf16
  GEMM(0, WERT,256,0,0, Aq,3072,1572864,256, EtB,512,1048576,262144, 512,512,256, 4,32);
  u16* P = A4;                // probs bf16
  k_softmax<<<16384,256,0,stream>>>(Sf, EtB, dist_w, P);
  u16* Ov = A1;               // [4096][1024] (AQKV dead after S/Et)
  GEMM(0, P,512,1048576,262144, VT,512,524288,131072, Ov,1024,524288,256, 512,256,512, 4,32);
  GEMM(2, Ov,1024,512,0, WO,1024,512,0, A5,1024,4194304,0, 4096,1024,512, 1,2);  // o-proj split-K
  k_res_ln2<<<4096,256,0,stream>>>(X, A5, Xb, ln4_w, ln4_b);

  // ---- FFN + LN5 ----
  GEMM(1, Xb,1024,0,0, WC3,1024,0,0, A1,4096,0,0, 4096,4096,1024, 1,1);
  GEMM(2, A1,4096,2048,0, WC4,4096,2048,0, A5,1024,4194304,0, 4096,1024,2048, 1,2); // c4 split-K
  k_res_ln2<<<4096,256,0,stream>>>(X, A5, Xb, ln5_w, ln5_b);

  // ---- output ----
  k_final<<<dim3(8,16,8),256,0,stream>>>(X, (float*)d_out);
}